// Round 19
// baseline (473.488 us; speedup 1.0000x reference)
//
#include <hip/hip_runtime.h>

typedef __attribute__((ext_vector_type(8)))  short bf16x8;
typedef __attribute__((ext_vector_type(16))) float f32x16;
typedef unsigned long long u64t;

// bank-spread swizzle on 16B units
__device__ __forceinline__ int swzu(int u)
{
    return u ^ (((u >> 3) & 1) | (((u >> 4) & 1) << 1));
}

// split fp32 -> (hi, lo) bf16 pair, RNE both
__device__ __forceinline__ void fsplit(float v, unsigned short& h, unsigned short& l)
{
    union { float f; unsigned u; } a; a.f = v;
    unsigned uh = a.u + 0x7fffu + ((a.u >> 16) & 1u);
    h = (unsigned short)(uh >> 16);
    union { float f; unsigned u; } hb; hb.u = (unsigned)h << 16;
    float r = v - hb.f;
    union { float f; unsigned u; } b; b.f = r;
    unsigned ul = b.u + 0x7fffu + ((b.u >> 16) & 1u);
    l = (unsigned short)(ul >> 16);
}

__device__ __forceinline__ float bf2f(unsigned short u)
{
    union { float f; unsigned v; } a; a.v = (unsigned)u << 16; return a.f;
}

// ---- ONE prep kernel: pack all weights + pack input + codebook norms/hist ----
struct PackDesc {
    const float* w;
    unsigned short *hi, *lo;
    int Co, Ci, KK, CoP, CiP;
    int blk0;
};
struct PrepArgs {
    PackDesc d[16];
    int nd;
    int nbw;                 // total weight-pack blocks
    const float* x;
    unsigned short* xPH;
    const float* cb;
    float* cn;
    int* hist;
    unsigned int* done;
};

__global__ __launch_bounds__(256) void prep(PrepArgs pa)
{
    int bx = blockIdx.x;
    if (bx < pa.nbw) {
        int di = 0;
#pragma unroll
        for (int i = 0; i < 16; i++)
            if (i < pa.nd && bx >= pa.d[i].blk0) di = i;
        const PackDesc& D = pa.d[di];
        int i = (bx - D.blk0) * 256 + threadIdx.x;
        int tot = D.KK * D.CoP * D.CiP;
        if (i >= tot) return;
        int t  = i / (D.CoP * D.CiP);
        int r  = i - t * (D.CoP * D.CiP);
        int co = r / D.CiP;
        int ci = r - co * D.CiP;
        float v = (co < D.Co && ci < D.Ci) ? D.w[((size_t)co * D.Ci + ci) * D.KK + t] : 0.f;
        unsigned short h, l;
        fsplit(v, h, l);
        D.hi[i] = h; D.lo[i] = l;
    } else if (bx < pa.nbw + 4096) {
        int idx = (bx - pa.nbw) * 256 + threadIdx.x;
        int n = idx >> 16, pix = idx & 65535;
        unsigned short h[8], l[8];
#pragma unroll
        for (int c = 0; c < 8; c++) h[c] = 0;
#pragma unroll
        for (int c = 0; c < 3; c++) {
            float v = pa.x[((size_t)(n * 3 + c) << 16) + pix];
            fsplit(v, h[c], l[c]);
        }
        uint4 hv;
        hv.x = h[0] | ((unsigned)h[1] << 16); hv.y = h[2] | ((unsigned)h[3] << 16);
        hv.z = h[4] | ((unsigned)h[5] << 16); hv.w = h[6] | ((unsigned)h[7] << 16);
        uint4 z4 = make_uint4(0, 0, 0, 0);
        size_t b0 = (((size_t)(n * 2) << 16) + pix) * 8;
        size_t b1 = (((size_t)(n * 2 + 1) << 16) + pix) * 8;
        *(uint4*)(pa.xPH + b0) = hv;
        *(uint4*)(pa.xPH + b1) = z4;
    } else {
        int i = (bx - pa.nbw - 4096) * 256 + threadIdx.x;
        if (i < 512) {
            pa.hist[i] = 0;
            float s = 0.f;
            for (int d = 0; d < 64; d++) s = fmaf(pa.cb[i*64+d], pa.cb[i*64+d], s);
            pa.cn[i] = s;
        }
        if (i == 0) *pa.done = 0u;
    }
}

// ============ bf16 MFMA direct conv (r10 structure) ============
template<int K,int S,int P,int CIP,int COUT,int HIN,int WIN,int HOUT,int WOUT,
         int TR,int TC,int WM,int WN,int PX2,int CO2,int CC,int CO_PAD,
         bool PACK,bool PRELU,bool PLO,bool WF32,bool ROUT,bool RES,bool GATHER>
__global__ __launch_bounds__(256) void conv_mfma(
    const unsigned short* __restrict__ inH,
    const unsigned short* __restrict__ wpH,
    const float* __restrict__ bias, const float* __restrict__ res,
    float* __restrict__ outF, unsigned short* __restrict__ outPH,
    unsigned short* __restrict__ outPL,
    const unsigned short* __restrict__ gcb, const unsigned short* __restrict__ gidx)
{
    constexpr int IHT = (TR - 1) * S + K;
    constexpr int IW  = (TC - 1) * S + K;
    constexpr int PS  = IHT * IW;
    constexpr int PLN = CC * 2;
    constexpr int UN  = PS * PLN;
    constexpr int KK  = K * K;
    constexpr int NCH = CIP / (CC * 16);
    constexpr int CG  = CIP / 8;
    constexpr int CGO = (COUT + 7) / 8;
    constexpr int XB  = WOUT / TC;
    constexpr int REGU = (UN + 255) / 256;
    constexpr int NST = CC * KK;

    __shared__ uint4 lbH[UN];

    const int tid = threadIdx.x;
    const int bx  = blockIdx.x;
    const int r0  = (bx / XB) * TR;
    const int c0  = (bx % XB) * TC;
    const int co0 = blockIdx.y * (WM * CO2 * 32);
    const int n   = blockIdx.z;

    const int l  = tid & 63, wv = tid >> 6;
    const int wm = wv / WN, wn = wv % WN;
    const int ln = l & 31, kg = l >> 5;

    int pb[PX2], gyv[PX2], gxv[PX2];
#pragma unroll
    for (int p2 = 0; p2 < PX2; p2++) {
        int q = wn * (PX2 * 32) + p2 * 32 + ln;
        int lr = q / TC, lc = q % TC;
        pb[p2] = (lr * S) * IW + lc * S;
        gyv[p2] = r0 + lr; gxv[p2] = c0 + lc;
    }

    const int iy0 = r0 * S - P, ix0 = c0 * S - P;
    const size_t inb = (size_t)n * CG * HIN * WIN;

    f32x16 acc[PX2][CO2];
#pragma unroll
    for (int p2 = 0; p2 < PX2; p2++)
#pragma unroll
        for (int g = 0; g < CO2; g++) acc[p2][g] = (f32x16){};

    auto unit_load = [&](int u, int cgb, uint4& hv){
        int kgu = u / PS, pos = u - kgu * PS;
        int py = pos / IW, px = pos - py * IW;
        int gy = iy0 + py, gx = ix0 + px;
        bool ok = ((unsigned)gy < (unsigned)HIN) && ((unsigned)gx < (unsigned)WIN);
        hv = make_uint4(0,0,0,0);
        if (ok) {
            if constexpr (GATHER) {
                int id = gidx[(size_t)n * (HIN * WIN) + (size_t)gy * WIN + gx];
                hv = *(const uint4*)(gcb + ((size_t)id * 64 + (size_t)(cgb + kgu) * 8));
            } else {
                size_t a = (inb + ((size_t)(cgb + kgu) * HIN + gy) * WIN + gx) * 8;
                hv = *(const uint4*)(inH + a);
            }
        }
    };

    auto stage_direct = [&](int kc){
        for (int idx = tid; idx < UN; idx += 256) {
            uint4 hv;
            unit_load(idx, kc * PLN, hv);
            lbH[swzu(idx)] = hv;
        }
    };

    uint4 rvH[REGU];
    auto load_regs = [&](int kc){
#pragma unroll
        for (int rr = 0; rr < REGU; rr++) {
            int idx = tid + rr * 256;
            uint4 hv = make_uint4(0,0,0,0);
            if (idx < UN) unit_load(idx, kc * PLN, hv);
            rvH[rr] = hv;
        }
    };
    auto write_regs = [&](){
#pragma unroll
        for (int rr = 0; rr < REGU; rr++) {
            int idx = tid + rr * 256;
            if (idx < UN) lbH[swzu(idx)] = rvH[rr];
        }
    };

    auto compute = [&](int kc){
        bf16x8 aC[CO2], aN[CO2], bC[PX2], bN[PX2];
        auto loadA = [&](int step, bf16x8* a){
            const int ks = step / KK, t = step - ks * KK;
#pragma unroll
            for (int g = 0; g < CO2; g++) {
                const int coA = co0 + (wm * CO2 + g) * 32 + ln;
                const size_t wo = ((size_t)t * CO_PAD + coA) * CIP
                                + kc * (CC * 16) + ks * 16 + kg * 8;
                a[g] = *(const bf16x8*)(wpH + wo);
            }
        };
        auto loadB = [&](int step, bf16x8* b){
            const int ks = step / KK, t = step - ks * KK;
            const int ky = t / K, kx = t - ky * K;
#pragma unroll
            for (int p2 = 0; p2 < PX2; p2++) {
                const int u = (ks * 2 + kg) * PS + pb[p2] + ky * IW + kx;
                b[p2] = *(const bf16x8*)&lbH[swzu(u)];
            }
        };
        loadA(0, aC); loadB(0, bC);
#pragma unroll
        for (int step = 0; step < NST; step++) {
            if (step + 1 < NST) { loadA(step + 1, aN); loadB(step + 1, bN); }
#pragma unroll
            for (int p2 = 0; p2 < PX2; p2++)
#pragma unroll
                for (int g = 0; g < CO2; g++)
                    acc[p2][g] = __builtin_amdgcn_mfma_f32_32x32x16_bf16(
                        aC[g], bC[p2], acc[p2][g], 0, 0, 0);
            if (step + 1 < NST) {
#pragma unroll
                for (int g = 0; g < CO2; g++) aC[g] = aN[g];
#pragma unroll
                for (int p2 = 0; p2 < PX2; p2++) bC[p2] = bN[p2];
            }
        }
    };

    stage_direct(0);
    __syncthreads();
    for (int kc = 0; kc < NCH; kc++) {
        const bool more = (kc + 1 < NCH);
        if (more) load_regs(kc + 1);
        compute(kc);
        if (more) {
            __syncthreads();
            write_regs();
            __syncthreads();
        }
    }

    const size_t HWo = (size_t)HOUT * WOUT;
#pragma unroll
    for (int p2 = 0; p2 < PX2; p2++) {
        const int gy = gyv[p2], gx = gxv[p2];
#pragma unroll
        for (int g = 0; g < CO2; g++) {
            const int co32 = co0 + (wm * CO2 + g) * 32;
#pragma unroll
            for (int rq = 0; rq < 4; rq++) {
                const int cb4 = co32 + 8 * rq + 4 * kg;
                float v[4];
#pragma unroll
                for (int i = 0; i < 4; i++) {
                    const int r = rq * 4 + i;
                    const int co = cb4 + i;
                    float bv = (co < COUT) ? bias[co] : 0.f;
                    float vv = acc[p2][g][r] + bv;
                    if (RES && co < COUT)
                        vv += res[((size_t)n * COUT + co) * HWo + (size_t)gy * WOUT + gx];
                    if (ROUT) vv = fmaxf(vv, 0.f);
                    if (WF32 && co < COUT)
                        outF[((size_t)n * COUT + co) * HWo + (size_t)gy * WOUT + gx] = vv;
                    v[i] = vv;
                }
                if (PACK) {
                    u64t uh = 0, ul = 0;
#pragma unroll
                    for (int i = 0; i < 4; i++) {
                        float pv = PRELU ? fmaxf(v[i], 0.f) : v[i];
                        unsigned short ph, pl;
                        fsplit(pv, ph, pl);
                        uh |= (u64t)ph << (16 * i);
                        ul |= (u64t)pl << (16 * i);
                    }
                    size_t pa = (((size_t)n * CGO + (co32 >> 3) + rq) * HOUT + gy) * (size_t)WOUT * 8
                              + (size_t)gx * 8 + 4 * kg;
                    *(u64t*)(outPH + pa) = uh;
                    if (PLO) *(u64t*)(outPL + pa) = ul;
                }
            }
        }
    }
}

// ============ FUSED residual block (r17, unchanged) ============
__global__ __launch_bounds__(256) void fused_res(
    const unsigned short* __restrict__ inH,
    const unsigned short* __restrict__ w3H,
    const float* __restrict__ b3,
    const unsigned short* __restrict__ w1H,
    const float* __restrict__ b1,
    float* __restrict__ Cf,
    unsigned short* __restrict__ outPH)
{
    constexpr int H = 64, W = 64;
    constexpr int IHT = 4, IW = 66, PS = IHT * IW;
    constexpr int CC = 2, PLN = 4, UN = PS * PLN;
    constexpr int NCH = 4, NST = 18;
    constexpr int REGU = (UN + 255) / 256;
    constexpr int CG = 16, CGO = 16;

    __shared__ uint4 lbH[UN];
    __shared__ unsigned short midL[4 * 128 * 8];

    const int tid = threadIdx.x;
    const int r0  = blockIdx.x * 2;
    const int n   = blockIdx.z;
    const int l  = tid & 63, wv = tid >> 6;
    const int ln = l & 31, kg = l >> 5;

    const int pxl1 = wv * 32 + ln;
    const int lr1 = pxl1 / W, lc1 = pxl1 % W;
    const int pb1 = lr1 * IW + lc1;

    const int iy0 = r0 - 1, ix0 = -1;
    const size_t inb = (size_t)n * CG * H * W;

    auto unit_load = [&](int u, int cgb, uint4& hv){
        int kgu = u / PS, pos = u - kgu * PS;
        int py = pos / IW, px = pos - py * IW;
        int gy = iy0 + py, gx = ix0 + px;
        bool ok = ((unsigned)gy < (unsigned)H) && ((unsigned)gx < (unsigned)W);
        hv = make_uint4(0,0,0,0);
        if (ok) {
            size_t a = (inb + ((size_t)(cgb + kgu) * H + gy) * W + gx) * 8;
            hv = *(const uint4*)(inH + a);
        }
    };
    auto stage_direct = [&](int kc){
        for (int idx = tid; idx < UN; idx += 256) {
            uint4 hv;
            unit_load(idx, kc * PLN, hv);
            lbH[swzu(idx)] = hv;
        }
    };
    uint4 rvH[REGU];
    auto load_regs = [&](int kc){
#pragma unroll
        for (int rr = 0; rr < REGU; rr++) {
            int idx = tid + rr * 256;
            uint4 hv = make_uint4(0,0,0,0);
            if (idx < UN) unit_load(idx, kc * PLN, hv);
            rvH[rr] = hv;
        }
    };
    auto write_regs = [&](){
#pragma unroll
        for (int rr = 0; rr < REGU; rr++) {
            int idx = tid + rr * 256;
            if (idx < UN) lbH[swzu(idx)] = rvH[rr];
        }
    };

    f32x16 acc1 = {};
    auto compute = [&](int kc){
        bf16x8 aC, aN, bC, bN;
        auto loadA = [&](int step, bf16x8& a){
            const int ks = step / 9, t = step - ks * 9;
            a = *(const bf16x8*)(w3H + ((size_t)t * 32 + ln) * 128
                                 + kc * 32 + ks * 16 + kg * 8);
        };
        auto loadB = [&](int step, bf16x8& b){
            const int ks = step / 9, t = step - ks * 9;
            const int ky = t / 3, kx = t - ky * 3;
            const int u = (ks * 2 + kg) * PS + pb1 + ky * IW + kx;
            b = *(const bf16x8*)&lbH[swzu(u)];
        };
        loadA(0, aC); loadB(0, bC);
#pragma unroll
        for (int step = 0; step < NST; step++) {
            if (step + 1 < NST) { loadA(step + 1, aN); loadB(step + 1, bN); }
            acc1 = __builtin_amdgcn_mfma_f32_32x32x16_bf16(aC, bC, acc1, 0, 0, 0);
            if (step + 1 < NST) { aC = aN; bC = bN; }
        }
    };

    stage_direct(0);
    __syncthreads();
    for (int kc = 0; kc < NCH; kc++) {
        const bool more = (kc + 1 < NCH);
        if (more) load_regs(kc + 1);
        compute(kc);
        if (more) {
            __syncthreads();
            write_regs();
            __syncthreads();
        }
    }

#pragma unroll
    for (int r = 0; r < 16; r++) {
        const int co = (r & 3) + 8 * (r >> 2) + 4 * kg;
        float vv = fmaxf(acc1[r] + b3[co], 0.f);
        unsigned short h, lo_;
        fsplit(vv, h, lo_);
        midL[((co >> 3) * 128 + pxl1) * 8 + (co & 7)] = h;
    }
    __syncthreads();

    f32x16 acc2[4];
#pragma unroll
    for (int pg = 0; pg < 4; pg++) acc2[pg] = (f32x16){};
#pragma unroll
    for (int pg = 0; pg < 4; pg++) {
#pragma unroll
        for (int ks = 0; ks < 2; ks++) {
            bf16x8 b = *(const bf16x8*)&midL[((ks * 2 + kg) * 128 + pg * 32 + ln) * 8];
            bf16x8 a = *(const bf16x8*)(w1H + ((size_t)(wv * 32 + ln)) * 32
                                        + ks * 16 + kg * 8);
            acc2[pg] = __builtin_amdgcn_mfma_f32_32x32x16_bf16(a, b, acc2[pg], 0, 0, 0);
        }
    }

    const int co32 = wv * 32;
#pragma unroll
    for (int pg = 0; pg < 4; pg++) {
        const int pxl = pg * 32 + ln;
        const int gy = r0 + pxl / W, gx = pxl % W;
#pragma unroll
        for (int rq = 0; rq < 4; rq++) {
            const int cb4 = co32 + 8 * rq + 4 * kg;
            float v[4];
#pragma unroll
            for (int i = 0; i < 4; i++) {
                const int r = rq * 4 + i;
                const int co = cb4 + i;
                size_t ra = ((size_t)n * 128 + co) * (H * W) + (size_t)gy * W + gx;
                float vv = acc2[pg][r] + b1[co] + Cf[ra];
                Cf[ra] = vv;
                v[i] = vv;
            }
            u64t uh = 0;
#pragma unroll
            for (int i = 0; i < 4; i++) {
                float pv = fmaxf(v[i], 0.f);
                unsigned short ph, pl;
                fsplit(pv, ph, pl);
                uh |= (u64t)ph << (16 * i);
            }
            size_t pa = (((size_t)n * CGO + (co32 >> 3) + rq) * H + gy) * (size_t)W * 8
                      + (size_t)gx * 8 + 4 * kg;
            *(u64t*)(outPH + pa) = uh;
        }
    }
}

// ============ bf16 MFMA transpose conv k=4 s=2 p=1 (r10 structure) ============
template<int CIP,int COUT,int HIN,int WIN,int CO2,int CC,int CO_PAD,
         bool PACK,bool WF32,bool ROUT>
__global__ __launch_bounds__(256) void convt_mfma(
    const unsigned short* __restrict__ inH,
    const unsigned short* __restrict__ wpH,
    const float* __restrict__ bias, float* __restrict__ outF,
    unsigned short* __restrict__ outPH)
{
    constexpr int HOUT = 2 * HIN, WOUT = 2 * WIN;
    constexpr int XHN  = WOUT / 128;
    constexpr int PS   = 3 * 68;
    constexpr int PLN  = CC * 2;
    constexpr int UN   = PS * PLN;
    constexpr int NCH  = CIP / (CC * 16);
    constexpr int CG   = CIP / 8;
    constexpr int CGO  = (COUT + 7) / 8;
    constexpr int REGU = (UN + 255) / 256;
    constexpr int NST  = CC * 4;

    __shared__ uint4 lbH[UN];

    const int tid = threadIdx.x;
    const int xh  = blockIdx.x % XHN;
    const int gr  = blockIdx.x / XHN;
    const int oy0 = (gr >> 1) * 4 + (gr & 1);
    const int co0 = blockIdx.y * (CO2 * 32);
    const int n   = blockIdx.z;

    const int ky0 = oy0 & 1;
    const int iyb = ((oy0 + ky0) >> 1) - 1;

    const int l  = tid & 63, wv = tid >> 6;
    const int pw = wv & 1, xb = wv >> 1;
    const int ln = l & 31, kg = l >> 5;

    const size_t inb = (size_t)n * CG * HIN * WIN;

    f32x16 acc[2][CO2];
#pragma unroll
    for (int r2 = 0; r2 < 2; r2++)
#pragma unroll
        for (int g = 0; g < CO2; g++) acc[r2][g] = (f32x16){};

    auto unit_load = [&](int u, int cgb, uint4& hv){
        int kgu = u / PS, pos = u - kgu * PS;
        int rr = pos / 68, cc = pos - rr * 68;
        int gy = iyb + rr, gx = xh * 64 + cc - 1;
        bool ok = ((unsigned)gy < (unsigned)HIN) && ((unsigned)gx < (unsigned)WIN);
        hv = make_uint4(0,0,0,0);
        if (ok) {
            size_t a = (inb + ((size_t)(cgb + kgu) * HIN + gy) * WIN + gx) * 8;
            hv = *(const uint4*)(inH + a);
        }
    };

    auto stage_direct = [&](int kc){
        for (int idx = tid; idx < UN; idx += 256) {
            uint4 hv;
            unit_load(idx, kc * PLN, hv);
            lbH[swzu(idx)] = hv;
        }
    };

    uint4 rvH[REGU];
    auto load_regs = [&](int kc){
#pragma unroll
        for (int rr = 0; rr < REGU; rr++) {
            int idx = tid + rr * 256;
            uint4 hv = make_uint4(0,0,0,0);
            if (idx < UN) unit_load(idx, kc * PLN, hv);
            rvH[rr] = hv;
        }
    };
    auto write_regs = [&](){
#pragma unroll
        for (int rr = 0; rr < REGU; rr++) {
            int idx = tid + rr * 256;
            if (idx < UN) lbH[swzu(idx)] = rvH[rr];
        }
    };

    auto compute = [&](int kc){
        bf16x8 aC[CO2], aN[CO2], bC[2], bN[2];
        auto loadA = [&](int step, bf16x8* a){
            const int ks = step / 4, tt = step - ks * 4;
            const int widx = (ky0 + 2 * (tt >> 1)) * 4 + (pw + 2 * (tt & 1));
#pragma unroll
            for (int g = 0; g < CO2; g++) {
                const int coA = co0 + g * 32 + ln;
                const size_t wo = ((size_t)widx * CO_PAD + coA) * CIP
                                + kc * (CC * 16) + ks * 16 + kg * 8;
                a[g] = *(const bf16x8*)(wpH + wo);
            }
        };
        auto loadB = [&](int step, bf16x8* bv){
            const int ks = step / 4, tt = step - ks * 4;
            const int ty = tt >> 1, tx = tt & 1;
#pragma unroll
            for (int r2 = 0; r2 < 2; r2++) {
                const int u = (ks * 2 + kg) * PS + (r2 + ty) * 68 + xb * 32 + ln + pw + tx;
                bv[r2] = *(const bf16x8*)&lbH[swzu(u)];
            }
        };
        loadA(0, aC); loadB(0, bC);
#pragma unroll
        for (int step = 0; step < NST; step++) {
            if (step + 1 < NST) { loadA(step + 1, aN); loadB(step + 1, bN); }
#pragma unroll
            for (int r2 = 0; r2 < 2; r2++)
#pragma unroll
                for (int g = 0; g < CO2; g++)
                    acc[r2][g] = __builtin_amdgcn_mfma_f32_32x32x16_bf16(
                        aC[g], bC[r2], acc[r2][g], 0, 0, 0);
            if (step + 1 < NST) {
#pragma unroll
                for (int g = 0; g < CO2; g++) aC[g] = aN[g];
#pragma unroll
                for (int r2 = 0; r2 < 2; r2++) bC[r2] = bN[r2];
            }
        }
    };

    stage_direct(0);
    __syncthreads();
    for (int kc = 0; kc < NCH; kc++) {
        const bool more = (kc + 1 < NCH);
        if (more) load_regs(kc + 1);
        compute(kc);
        if (more) {
            __syncthreads();
            write_regs();
            __syncthreads();
        }
    }

    const int ox = xh * 128 + pw + 2 * (xb * 32 + ln);
    const size_t HWo = (size_t)HOUT * WOUT;
#pragma unroll
    for (int r2 = 0; r2 < 2; r2++) {
        const int oy = oy0 + 2 * r2;
#pragma unroll
        for (int g = 0; g < CO2; g++) {
            const int co32 = co0 + g * 32;
#pragma unroll
            for (int rq = 0; rq < 4; rq++) {
                const int cb4 = co32 + 8 * rq + 4 * kg;
                float v[4];
#pragma unroll
                for (int i = 0; i < 4; i++) {
                    const int r = rq * 4 + i;
                    const int co = cb4 + i;
                    float bv = (co < COUT) ? bias[co] : 0.f;
                    float vv = acc[r2][g][r] + bv;
                    if (ROUT) vv = fmaxf(vv, 0.f);
                    if (WF32 && co < COUT)
                        outF[((size_t)n * COUT + co) * HWo + (size_t)oy * WOUT + ox] = vv;
                    v[i] = vv;
                }
                if (PACK) {
                    u64t uh = 0;
#pragma unroll
                    for (int i = 0; i < 4; i++) {
                        unsigned short ph, pl;
                        fsplit(v[i], ph, pl);
                        uh |= (u64t)ph << (16 * i);
                    }
                    size_t pa = (((size_t)n * CGO + (co32 >> 3) + rq) * HOUT + oy) * (size_t)WOUT * 8
                              + (size_t)ox * 8 + 4 * kg;
                    *(u64t*)(outPH + pa) = uh;
                }
            }
        }
    }
}

// ====== FUSED pre-VQ 1x1 + VQ + last-block finalize ======
__global__ __launch_bounds__(256) void vq_fused(
    const unsigned short* __restrict__ C1PH,
    const unsigned short* __restrict__ preH,
    const float* __restrict__ pre_b,
    const unsigned short* __restrict__ cbH, const unsigned short* __restrict__ cbL,
    const float* __restrict__ cnorm,
    unsigned short* __restrict__ IDX,
    float* __restrict__ ssep, int* __restrict__ hist,
    unsigned int* __restrict__ done,
    float* __restrict__ o_loss, float* __restrict__ o_perp)
{
    __shared__ unsigned short zH[128 * 72];
    __shared__ unsigned short zL[128 * 72];
    __shared__ float cnl[512];
    __shared__ int   hl[512];
    __shared__ int   lastBlk;

    const int tid = threadIdx.x;
    const int blk = blockIdx.x;

    for (int i = tid; i < 512; i += 256) { cnl[i] = cnorm[i]; hl[i] = 0; }

    const int l  = tid & 63, wv = tid >> 6;
    const int ln = l & 31, kg = l >> 5;
    const int tok = wv * 32 + ln;
    const int t   = blk * 128 + tok;
    const int n   = t >> 12, pix = t & 4095;

    // phase 1: z = pre_w x relu(C1) (1x1), kc ascending
    f32x16 az[2];
    az[0] = (f32x16){}; az[1] = (f32x16){};
#pragma unroll
    for (int kc = 0; kc < 8; kc++) {
        bf16x8 b = *(const bf16x8*)(C1PH + ((size_t)(n * 16 + kc * 2 + kg) * 4096 + pix) * 8);
#pragma unroll
        for (int g = 0; g < 2; g++) {
            bf16x8 a = *(const bf16x8*)(preH + ((size_t)(g * 32 + ln)) * 128
                                        + kc * 16 + kg * 8);
            az[g] = __builtin_amdgcn_mfma_f32_32x32x16_bf16(a, b, az[g], 0, 0, 0);
        }
    }
#pragma unroll
    for (int g = 0; g < 2; g++)
#pragma unroll
        for (int r = 0; r < 16; r++) {
            const int d = g * 32 + (r & 3) + 8 * (r >> 2) + 4 * kg;
            float vv = az[g][r] + pre_b[d];
            unsigned short h, lo_;
            fsplit(vv, h, lo_);
            zH[tok * 72 + d] = h;
            zL[tok * 72 + d] = lo_;
        }
    __syncthreads();

    // phase 2: VQ search
    float xn = 0.f;
#pragma unroll
    for (int j8 = 0; j8 < 8; j8++) {
        bf16x8 vH = *(const bf16x8*)&zH[tok * 72 + j8 * 8];
        bf16x8 vL = *(const bf16x8*)&zL[tok * 72 + j8 * 8];
#pragma unroll
        for (int j = 0; j < 8; j++) {
            float xv = bf2f((unsigned short)vH[j]) + bf2f((unsigned short)vL[j]);
            xn = fmaf(xv, xv, xn);
        }
    }

    float bm = 3.4e38f; int bidx = 0;
    for (int cg = 0; cg < 16; cg++) {
        f32x16 a0 = {}, a1 = {};
#pragma unroll
        for (int ks = 0; ks < 4; ks++) {
            const size_t wo = ((size_t)(cg * 32 + ln)) * 64 + ks * 16 + kg * 8;
            bf16x8 aH = *(const bf16x8*)(cbH + wo);
            bf16x8 aL = *(const bf16x8*)(cbL + wo);
            bf16x8 bH = *(const bf16x8*)&zH[tok * 72 + ks * 16 + kg * 8];
            bf16x8 bL = *(const bf16x8*)&zL[tok * 72 + ks * 16 + kg * 8];
            a0 = __builtin_amdgcn_mfma_f32_32x32x16_bf16(aH, bH, a0, 0, 0, 0);
            a1 = __builtin_amdgcn_mfma_f32_32x32x16_bf16(aH, bL, a1, 0, 0, 0);
            a1 = __builtin_amdgcn_mfma_f32_32x32x16_bf16(aL, bH, a1, 0, 0, 0);
        }
#pragma unroll
        for (int r = 0; r < 16; r++) {
            int m    = (r & 3) + 8 * (r >> 2) + 4 * kg;
            int code = cg * 32 + m;
            float s  = a0[r] + a1[r];
            float dm = cnl[code] - 2.f * s;
            if (dm < bm) { bm = dm; bidx = code; }
        }
    }

    float bm2 = __shfl_xor(bm, 32);
    int   bi2 = __shfl_xor(bidx, 32);
    if (bm2 < bm || (bm2 == bm && bi2 < bidx)) { bm = bm2; bidx = bi2; }

    if (kg == 0) IDX[t] = (unsigned short)bidx;

    float bestd = xn + bm;
    float c = (kg == 0) ? bestd : 0.f;
#pragma unroll
    for (int o = 32; o > 0; o >>= 1) c += __shfl_down(c, o, 64);
    if (l == 0) ssep[blk * 4 + wv] = c;
    if (kg == 0) atomicAdd(&hl[bidx], 1);
    __syncthreads();
    for (int i = tid; i < 512; i += 256) if (hl[i] > 0) atomicAdd(&hist[i], hl[i]);

    // last-block finalize (deterministic: reads fully-written SSE/HIST)
    if (tid == 0) {
        __threadfence();
        unsigned int prev = atomicAdd(done, 1u);
        lastBlk = (prev == gridDim.x - 1) ? 1 : 0;
    }
    __syncthreads();
    if (lastBlk) {
        __threadfence();
        float* red = (float*)zH;   // reuse LDS
        float h = 0.f;
        for (int i = tid; i < 512; i += 256) {
            float p = (float)hist[i] * (1.0f / 65536.0f);
            h -= p * logf(p + 1e-10f);
        }
        red[tid] = h;
        __syncthreads();
        for (int st = 128; st > 0; st >>= 1) {
            if (tid < st) red[tid] += red[tid + st];
            __syncthreads();
        }
        const float H = red[0];
        __syncthreads();
        float s = 0.f;
        for (int i = tid; i < 2048; i += 256) s += ssep[i];
        red[tid] = s;
        __syncthreads();
        for (int st = 128; st > 0; st >>= 1) {
            if (tid < st) red[tid] += red[tid + st];
            __syncthreads();
        }
        if (tid == 0) {
            *o_loss = 1.25f * red[0] / 4194304.0f;
            *o_perp = expf(H);
        }
    }
}

extern "C" void kernel_launch(void* const* d_in, const int* in_sizes, int n_in,
                              void* d_out, int out_size, void* d_ws, size_t ws_size,
                              hipStream_t stream)
{
    const float* x       = (const float*)d_in[0];
    const float* enc_w1  = (const float*)d_in[1];
    const float* enc_b1  = (const float*)d_in[2];
    const float* enc_w2  = (const float*)d_in[3];
    const float* enc_b2  = (const float*)d_in[4];
    const float* enc_w3  = (const float*)d_in[5];
    const float* enc_b3  = (const float*)d_in[6];
    const float* enc_rw3 = (const float*)d_in[7];
    const float* enc_rb3 = (const float*)d_in[8];
    const float* enc_rw1 = (const float*)d_in[9];
    const float* enc_rb1 = (const float*)d_in[10];
    const float* pre_w   = (const float*)d_in[11];
    const float* pre_b   = (const float*)d_in[12];
    const float* cb      = (const float*)d_in[13];
    const float* dec_w1  = (const float*)d_in[14];
    const float* dec_b1  = (const float*)d_in[15];
    const float* dec_rw3 = (const float*)d_in[16];
    const float* dec_rb3 = (const float*)d_in[17];
    const float* dec_rw1 = (const float*)d_in[18];
    const float* dec_rb1 = (const float*)d_in[19];
    const float* dw1     = (const float*)d_in[20];
    const float* db1     = (const float*)d_in[21];
    const float* dw2     = (const float*)d_in[22];
    const float* db2     = (const float*)d_in[23];

    float* o      = (float*)d_out;
    float* loss_p = o;
    float* recon  = o + 1;
    float* perp_p = o + 1 + 16 * 3 * 256 * 256;

    unsigned short* R1H = (unsigned short*)d_ws;
    unsigned short* R1L = R1H + 16777216;
    unsigned short* R2H = R1L + 16777216;
    unsigned short* R2L = R2H + 16777216;
    float* Cf  = (float*)(R2L + 16777216);
    float* SSE = Cf + 8388608;
    int*   HIST = (int*)(SSE + 2048);
    unsigned int* DONE = (unsigned int*)(HIST + 512);
    unsigned short* IDXb = (unsigned short*)(DONE + 8);   // 65536 tokens

    // packed activation aliases (lifetime-disjoint)
    unsigned short *xPH = R1H;
    unsigned short *BPH = R1H;
    unsigned short *dAPH = R1H;
    unsigned short *APH = R2H;
    unsigned short *C1PH = R2H;          // ping
    unsigned short *C2PH = R2L;          // pong

    unsigned short* wp_cur = (unsigned short*)(((size_t)(IDXb + 65536) + 31) & ~(size_t)31);
    auto carve = [&](size_t n_us) {
        unsigned short* p = wp_cur;
        wp_cur += ((n_us + 15) & ~(size_t)15);
        return p;
    };

    unsigned short *e1H = carve(16*64*16),  *e1L = carve(16*64*16);
    unsigned short *e2H = carve(16*128*64), *e2L = carve(16*128*64);
    unsigned short *e3H = carve(9*128*128), *e3L = carve(9*128*128);
    unsigned short *er3aH = carve(9*32*128), *er3aL = carve(9*32*128);
    unsigned short *er3bH = carve(9*32*128), *er3bL = carve(9*32*128);
    unsigned short *er1aH = carve(128*32),   *er1aL = carve(128*32);
    unsigned short *er1bH = carve(128*32),   *er1bL = carve(128*32);
    unsigned short *preH = carve(64*128),    *preL = carve(64*128);
    unsigned short *d1H  = carve(9*128*64),  *d1L  = carve(9*128*64);
    unsigned short *dr3aH = carve(9*32*128), *dr3aL = carve(9*32*128);
    unsigned short *dr3bH = carve(9*32*128), *dr3bL = carve(9*32*128);
    unsigned short *dr1aH = carve(128*32),   *dr1aL = carve(128*32);
    unsigned short *dr1bH = carve(128*32),   *dr1bL = carve(128*32);
    unsigned short *ct1H = carve(16*64*128), *ct1L = carve(16*64*128);
    unsigned short *ct2H = carve(16*32*64),  *ct2L = carve(16*32*64);
    unsigned short *cbH  = carve(512*64),    *cbL  = carve(512*64);
    float* CN = (float*)carve(1024);

    PrepArgs pa; int nb = 0;
    auto addPK = [&](int i, const float* w, unsigned short* hi, unsigned short* lo,
                     int Co, int Ci, int KK, int CoP, int CiP) {
        pa.d[i] = {w, hi, lo, Co, Ci, KK, CoP, CiP, nb};
        nb += (KK * CoP * CiP + 255) / 256;
    };
    addPK(0,  enc_w1, e1H, e1L, 64, 3, 16, 64, 16);
    addPK(1,  enc_w2, e2H, e2L, 128, 64, 16, 128, 64);
    addPK(2,  enc_w3, e3H, e3L, 128, 128, 9, 128, 128);
    addPK(3,  enc_rw3,            er3aH, er3aL, 32, 128, 9, 32, 128);
    addPK(4,  enc_rw3 + 32*128*9, er3bH, er3bL, 32, 128, 9, 32, 128);
    addPK(5,  enc_rw1,            er1aH, er1aL, 128, 32, 1, 128, 32);
    addPK(6,  enc_rw1 + 128*32,   er1bH, er1bL, 128, 32, 1, 128, 32);
    addPK(7,  pre_w, preH, preL, 64, 128, 1, 64, 128);
    addPK(8,  dec_w1, d1H, d1L, 128, 64, 9, 128, 64);
    addPK(9,  dec_rw3,            dr3aH, dr3aL, 32, 128, 9, 32, 128);
    addPK(10, dec_rw3 + 32*128*9, dr3bH, dr3bL, 32, 128, 9, 32, 128);
    addPK(11, dec_rw1,            dr1aH, dr1aL, 128, 32, 1, 128, 32);
    addPK(12, dec_rw1 + 128*32,   dr1bH, dr1bL, 128, 32, 1, 128, 32);
    addPK(13, dw1, ct1H, ct1L, 64, 128, 16, 64, 128);
    addPK(14, dw2, ct2H, ct2L, 3, 64, 16, 32, 64);
    addPK(15, cb,  cbH,  cbL,  512, 64, 1, 512, 64);
    pa.nd = 16;
    pa.nbw = nb;
    pa.x = x; pa.xPH = xPH; pa.cb = cb; pa.cn = CN; pa.hist = HIST; pa.done = DONE;
    prep<<<dim3(nb + 4096 + 2), dim3(256), 0, stream>>>(pa);

    const int N = 16;

    // ---- encoder ----
    conv_mfma<4,2,1, 16,64, 256,256, 128,128, 2,64, 2,2,2,1, 1, 64,
              true,false,false,false,true,false,false>
        <<<dim3(128,1,N),256,0,stream>>>(xPH, e1H, enc_b1, nullptr, nullptr, APH, nullptr,
                                         nullptr, nullptr);
    conv_mfma<4,2,1, 64,128, 128,128, 64,64, 2,64, 2,2,2,2, 1, 128,
              true,false,false,false,true,false,false>
        <<<dim3(32,1,N),256,0,stream>>>(APH, e2H, enc_b2, nullptr, nullptr, BPH, nullptr,
                                        nullptr, nullptr);
    conv_mfma<3,1,1, 128,128, 64,64, 64,64, 2,64, 2,2,2,2, 4, 128,
              true,true,false,true,false,false,false>
        <<<dim3(32,1,N),256,0,stream>>>(BPH, e3H, enc_b3, nullptr, Cf, C1PH, nullptr,
                                        nullptr, nullptr);
    fused_res<<<dim3(32,1,N),256,0,stream>>>(C1PH, er3aH, enc_rb3, er1aH, enc_rb1, Cf, C2PH);
    fused_res<<<dim3(32,1,N),256,0,stream>>>(C2PH, er3bH, enc_rb3 + 32, er1bH, enc_rb1 + 128, Cf, C1PH);

    // ---- fused pre-VQ 1x1 + VQ + finalize ----
    vq_fused<<<dim3(512), dim3(256), 0, stream>>>(C1PH, preH, pre_b, cbH, cbL, CN,
                                                  IDXb, SSE, HIST, DONE, loss_p, perp_p);

    // ---- decoder (dec1 gathers q rows by index) ----
    conv_mfma<3,1,1, 64,128, 64,64, 64,64, 2,64, 2,2,2,2, 4, 128,
              true,true,false,true,false,false,true>
        <<<dim3(32,1,N),256,0,stream>>>(nullptr, d1H, dec_b1, nullptr, Cf, C1PH, nullptr,
                                        cbH, IDXb);
    fused_res<<<dim3(32,1,N),256,0,stream>>>(C1PH, dr3aH, dec_rb3, dr1aH, dec_rb1, Cf, C2PH);
    fused_res<<<dim3(32,1,N),256,0,stream>>>(C2PH, dr3bH, dec_rb3 + 32, dr1bH, dec_rb1 + 128, Cf, C1PH);
    convt_mfma<128,64, 64,64, 2, 2, 64,  true,false,true>
        <<<dim3(64,1,N),256,0,stream>>>(C1PH, ct1H, db1, nullptr, dAPH);
    convt_mfma<64,3, 128,128, 1, 2, 32,  false,true,false>
        <<<dim3(256,1,N),256,0,stream>>>(dAPH, ct2H, db2, recon, nullptr);
}

// Round 20
// 451.783 us; speedup vs baseline: 1.0480x; 1.0480x over previous
//
#include <hip/hip_runtime.h>

typedef __attribute__((ext_vector_type(8)))  short bf16x8;
typedef __attribute__((ext_vector_type(16))) float f32x16;
typedef unsigned long long u64t;

// bank-spread swizzle on 16B units
__device__ __forceinline__ int swzu(int u)
{
    return u ^ (((u >> 3) & 1) | (((u >> 4) & 1) << 1));
}

// split fp32 -> (hi, lo) bf16 pair, RNE both
__device__ __forceinline__ void fsplit(float v, unsigned short& h, unsigned short& l)
{
    union { float f; unsigned u; } a; a.f = v;
    unsigned uh = a.u + 0x7fffu + ((a.u >> 16) & 1u);
    h = (unsigned short)(uh >> 16);
    union { float f; unsigned u; } hb; hb.u = (unsigned)h << 16;
    float r = v - hb.f;
    union { float f; unsigned u; } b; b.f = r;
    unsigned ul = b.u + 0x7fffu + ((b.u >> 16) & 1u);
    l = (unsigned short)(ul >> 16);
}

__device__ __forceinline__ float bf2f(unsigned short u)
{
    union { float f; unsigned v; } a; a.v = (unsigned)u << 16; return a.f;
}

// ---- ONE prep kernel: pack all weights + pack input + codebook norms/hist ----
struct PackDesc {
    const float* w;
    unsigned short *hi, *lo;
    int Co, Ci, KK, CoP, CiP;
    int blk0;
};
struct PrepArgs {
    PackDesc d[16];
    int nd;
    int nbw;                 // total weight-pack blocks
    const float* x;
    unsigned short* xPH;
    const float* cb;
    float* cn;
    int* hist;
    unsigned int* done;
};

__global__ __launch_bounds__(256) void prep(PrepArgs pa)
{
    int bx = blockIdx.x;
    if (bx < pa.nbw) {
        int di = 0;
#pragma unroll
        for (int i = 0; i < 16; i++)
            if (i < pa.nd && bx >= pa.d[i].blk0) di = i;
        const PackDesc& D = pa.d[di];
        int i = (bx - D.blk0) * 256 + threadIdx.x;
        int tot = D.KK * D.CoP * D.CiP;
        if (i >= tot) return;
        int t  = i / (D.CoP * D.CiP);
        int r  = i - t * (D.CoP * D.CiP);
        int co = r / D.CiP;
        int ci = r - co * D.CiP;
        float v = (co < D.Co && ci < D.Ci) ? D.w[((size_t)co * D.Ci + ci) * D.KK + t] : 0.f;
        unsigned short h, l;
        fsplit(v, h, l);
        D.hi[i] = h; D.lo[i] = l;
    } else if (bx < pa.nbw + 4096) {
        int idx = (bx - pa.nbw) * 256 + threadIdx.x;
        int n = idx >> 16, pix = idx & 65535;
        unsigned short h[8], l[8];
#pragma unroll
        for (int c = 0; c < 8; c++) h[c] = 0;
#pragma unroll
        for (int c = 0; c < 3; c++) {
            float v = pa.x[((size_t)(n * 3 + c) << 16) + pix];
            fsplit(v, h[c], l[c]);
        }
        uint4 hv;
        hv.x = h[0] | ((unsigned)h[1] << 16); hv.y = h[2] | ((unsigned)h[3] << 16);
        hv.z = h[4] | ((unsigned)h[5] << 16); hv.w = h[6] | ((unsigned)h[7] << 16);
        uint4 z4 = make_uint4(0, 0, 0, 0);
        size_t b0 = (((size_t)(n * 2) << 16) + pix) * 8;
        size_t b1 = (((size_t)(n * 2 + 1) << 16) + pix) * 8;
        *(uint4*)(pa.xPH + b0) = hv;
        *(uint4*)(pa.xPH + b1) = z4;
    } else {
        int i = (bx - pa.nbw - 4096) * 256 + threadIdx.x;
        if (i < 512) {
            pa.hist[i] = 0;
            float s = 0.f;
            for (int d = 0; d < 64; d++) s = fmaf(pa.cb[i*64+d], pa.cb[i*64+d], s);
            pa.cn[i] = s;
        }
        if (i == 0) *pa.done = 0u;
    }
}

// ============ bf16 MFMA direct conv (r10 structure) ============
template<int K,int S,int P,int CIP,int COUT,int HIN,int WIN,int HOUT,int WOUT,
         int TR,int TC,int WM,int WN,int PX2,int CO2,int CC,int CO_PAD,
         bool PACK,bool PRELU,bool PLO,bool WF32,bool ROUT,bool RES,bool GATHER>
__global__ __launch_bounds__(256) void conv_mfma(
    const unsigned short* __restrict__ inH,
    const unsigned short* __restrict__ wpH,
    const float* __restrict__ bias, const float* __restrict__ res,
    float* __restrict__ outF, unsigned short* __restrict__ outPH,
    unsigned short* __restrict__ outPL,
    const unsigned short* __restrict__ gcb, const unsigned short* __restrict__ gidx)
{
    constexpr int IHT = (TR - 1) * S + K;
    constexpr int IW  = (TC - 1) * S + K;
    constexpr int PS  = IHT * IW;
    constexpr int PLN = CC * 2;
    constexpr int UN  = PS * PLN;
    constexpr int KK  = K * K;
    constexpr int NCH = CIP / (CC * 16);
    constexpr int CG  = CIP / 8;
    constexpr int CGO = (COUT + 7) / 8;
    constexpr int XB  = WOUT / TC;
    constexpr int REGU = (UN + 255) / 256;
    constexpr int NST = CC * KK;

    __shared__ uint4 lbH[UN];

    const int tid = threadIdx.x;
    const int bx  = blockIdx.x;
    const int r0  = (bx / XB) * TR;
    const int c0  = (bx % XB) * TC;
    const int co0 = blockIdx.y * (WM * CO2 * 32);
    const int n   = blockIdx.z;

    const int l  = tid & 63, wv = tid >> 6;
    const int wm = wv / WN, wn = wv % WN;
    const int ln = l & 31, kg = l >> 5;

    int pb[PX2], gyv[PX2], gxv[PX2];
#pragma unroll
    for (int p2 = 0; p2 < PX2; p2++) {
        int q = wn * (PX2 * 32) + p2 * 32 + ln;
        int lr = q / TC, lc = q % TC;
        pb[p2] = (lr * S) * IW + lc * S;
        gyv[p2] = r0 + lr; gxv[p2] = c0 + lc;
    }

    const int iy0 = r0 * S - P, ix0 = c0 * S - P;
    const size_t inb = (size_t)n * CG * HIN * WIN;

    f32x16 acc[PX2][CO2];
#pragma unroll
    for (int p2 = 0; p2 < PX2; p2++)
#pragma unroll
        for (int g = 0; g < CO2; g++) acc[p2][g] = (f32x16){};

    auto unit_load = [&](int u, int cgb, uint4& hv){
        int kgu = u / PS, pos = u - kgu * PS;
        int py = pos / IW, px = pos - py * IW;
        int gy = iy0 + py, gx = ix0 + px;
        bool ok = ((unsigned)gy < (unsigned)HIN) && ((unsigned)gx < (unsigned)WIN);
        hv = make_uint4(0,0,0,0);
        if (ok) {
            if constexpr (GATHER) {
                int id = gidx[(size_t)n * (HIN * WIN) + (size_t)gy * WIN + gx];
                hv = *(const uint4*)(gcb + ((size_t)id * 64 + (size_t)(cgb + kgu) * 8));
            } else {
                size_t a = (inb + ((size_t)(cgb + kgu) * HIN + gy) * WIN + gx) * 8;
                hv = *(const uint4*)(inH + a);
            }
        }
    };

    auto stage_direct = [&](int kc){
        for (int idx = tid; idx < UN; idx += 256) {
            uint4 hv;
            unit_load(idx, kc * PLN, hv);
            lbH[swzu(idx)] = hv;
        }
    };

    uint4 rvH[REGU];
    auto load_regs = [&](int kc){
#pragma unroll
        for (int rr = 0; rr < REGU; rr++) {
            int idx = tid + rr * 256;
            uint4 hv = make_uint4(0,0,0,0);
            if (idx < UN) unit_load(idx, kc * PLN, hv);
            rvH[rr] = hv;
        }
    };
    auto write_regs = [&](){
#pragma unroll
        for (int rr = 0; rr < REGU; rr++) {
            int idx = tid + rr * 256;
            if (idx < UN) lbH[swzu(idx)] = rvH[rr];
        }
    };

    auto compute = [&](int kc){
        bf16x8 aC[CO2], aN[CO2], bC[PX2], bN[PX2];
        auto loadA = [&](int step, bf16x8* a){
            const int ks = step / KK, t = step - ks * KK;
#pragma unroll
            for (int g = 0; g < CO2; g++) {
                const int coA = co0 + (wm * CO2 + g) * 32 + ln;
                const size_t wo = ((size_t)t * CO_PAD + coA) * CIP
                                + kc * (CC * 16) + ks * 16 + kg * 8;
                a[g] = *(const bf16x8*)(wpH + wo);
            }
        };
        auto loadB = [&](int step, bf16x8* b){
            const int ks = step / KK, t = step - ks * KK;
            const int ky = t / K, kx = t - ky * K;
#pragma unroll
            for (int p2 = 0; p2 < PX2; p2++) {
                const int u = (ks * 2 + kg) * PS + pb[p2] + ky * IW + kx;
                b[p2] = *(const bf16x8*)&lbH[swzu(u)];
            }
        };
        loadA(0, aC); loadB(0, bC);
#pragma unroll
        for (int step = 0; step < NST; step++) {
            if (step + 1 < NST) { loadA(step + 1, aN); loadB(step + 1, bN); }
#pragma unroll
            for (int p2 = 0; p2 < PX2; p2++)
#pragma unroll
                for (int g = 0; g < CO2; g++)
                    acc[p2][g] = __builtin_amdgcn_mfma_f32_32x32x16_bf16(
                        aC[g], bC[p2], acc[p2][g], 0, 0, 0);
            if (step + 1 < NST) {
#pragma unroll
                for (int g = 0; g < CO2; g++) aC[g] = aN[g];
#pragma unroll
                for (int p2 = 0; p2 < PX2; p2++) bC[p2] = bN[p2];
            }
        }
    };

    stage_direct(0);
    __syncthreads();
    for (int kc = 0; kc < NCH; kc++) {
        const bool more = (kc + 1 < NCH);
        if (more) load_regs(kc + 1);
        compute(kc);
        if (more) {
            __syncthreads();
            write_regs();
            __syncthreads();
        }
    }

    const size_t HWo = (size_t)HOUT * WOUT;
#pragma unroll
    for (int p2 = 0; p2 < PX2; p2++) {
        const int gy = gyv[p2], gx = gxv[p2];
#pragma unroll
        for (int g = 0; g < CO2; g++) {
            const int co32 = co0 + (wm * CO2 + g) * 32;
#pragma unroll
            for (int rq = 0; rq < 4; rq++) {
                const int cb4 = co32 + 8 * rq + 4 * kg;
                float v[4];
#pragma unroll
                for (int i = 0; i < 4; i++) {
                    const int r = rq * 4 + i;
                    const int co = cb4 + i;
                    float bv = (co < COUT) ? bias[co] : 0.f;
                    float vv = acc[p2][g][r] + bv;
                    if (RES && co < COUT)
                        vv += res[((size_t)n * COUT + co) * HWo + (size_t)gy * WOUT + gx];
                    if (ROUT) vv = fmaxf(vv, 0.f);
                    if (WF32 && co < COUT)
                        outF[((size_t)n * COUT + co) * HWo + (size_t)gy * WOUT + gx] = vv;
                    v[i] = vv;
                }
                if (PACK) {
                    u64t uh = 0, ul = 0;
#pragma unroll
                    for (int i = 0; i < 4; i++) {
                        float pv = PRELU ? fmaxf(v[i], 0.f) : v[i];
                        unsigned short ph, pl;
                        fsplit(pv, ph, pl);
                        uh |= (u64t)ph << (16 * i);
                        ul |= (u64t)pl << (16 * i);
                    }
                    size_t pa = (((size_t)n * CGO + (co32 >> 3) + rq) * HOUT + gy) * (size_t)WOUT * 8
                              + (size_t)gx * 8 + 4 * kg;
                    *(u64t*)(outPH + pa) = uh;
                    if (PLO) *(u64t*)(outPL + pa) = ul;
                }
            }
        }
    }
}

// ============ FUSED residual block (r17, unchanged) ============
__global__ __launch_bounds__(256) void fused_res(
    const unsigned short* __restrict__ inH,
    const unsigned short* __restrict__ w3H,
    const float* __restrict__ b3,
    const unsigned short* __restrict__ w1H,
    const float* __restrict__ b1,
    float* __restrict__ Cf,
    unsigned short* __restrict__ outPH)
{
    constexpr int H = 64, W = 64;
    constexpr int IHT = 4, IW = 66, PS = IHT * IW;
    constexpr int CC = 2, PLN = 4, UN = PS * PLN;
    constexpr int NCH = 4, NST = 18;
    constexpr int REGU = (UN + 255) / 256;
    constexpr int CG = 16, CGO = 16;

    __shared__ uint4 lbH[UN];
    __shared__ unsigned short midL[4 * 128 * 8];

    const int tid = threadIdx.x;
    const int r0  = blockIdx.x * 2;
    const int n   = blockIdx.z;
    const int l  = tid & 63, wv = tid >> 6;
    const int ln = l & 31, kg = l >> 5;

    const int pxl1 = wv * 32 + ln;
    const int lr1 = pxl1 / W, lc1 = pxl1 % W;
    const int pb1 = lr1 * IW + lc1;

    const int iy0 = r0 - 1, ix0 = -1;
    const size_t inb = (size_t)n * CG * H * W;

    auto unit_load = [&](int u, int cgb, uint4& hv){
        int kgu = u / PS, pos = u - kgu * PS;
        int py = pos / IW, px = pos - py * IW;
        int gy = iy0 + py, gx = ix0 + px;
        bool ok = ((unsigned)gy < (unsigned)H) && ((unsigned)gx < (unsigned)W);
        hv = make_uint4(0,0,0,0);
        if (ok) {
            size_t a = (inb + ((size_t)(cgb + kgu) * H + gy) * W + gx) * 8;
            hv = *(const uint4*)(inH + a);
        }
    };
    auto stage_direct = [&](int kc){
        for (int idx = tid; idx < UN; idx += 256) {
            uint4 hv;
            unit_load(idx, kc * PLN, hv);
            lbH[swzu(idx)] = hv;
        }
    };
    uint4 rvH[REGU];
    auto load_regs = [&](int kc){
#pragma unroll
        for (int rr = 0; rr < REGU; rr++) {
            int idx = tid + rr * 256;
            uint4 hv = make_uint4(0,0,0,0);
            if (idx < UN) unit_load(idx, kc * PLN, hv);
            rvH[rr] = hv;
        }
    };
    auto write_regs = [&](){
#pragma unroll
        for (int rr = 0; rr < REGU; rr++) {
            int idx = tid + rr * 256;
            if (idx < UN) lbH[swzu(idx)] = rvH[rr];
        }
    };

    f32x16 acc1 = {};
    auto compute = [&](int kc){
        bf16x8 aC, aN, bC, bN;
        auto loadA = [&](int step, bf16x8& a){
            const int ks = step / 9, t = step - ks * 9;
            a = *(const bf16x8*)(w3H + ((size_t)t * 32 + ln) * 128
                                 + kc * 32 + ks * 16 + kg * 8);
        };
        auto loadB = [&](int step, bf16x8& b){
            const int ks = step / 9, t = step - ks * 9;
            const int ky = t / 3, kx = t - ky * 3;
            const int u = (ks * 2 + kg) * PS + pb1 + ky * IW + kx;
            b = *(const bf16x8*)&lbH[swzu(u)];
        };
        loadA(0, aC); loadB(0, bC);
#pragma unroll
        for (int step = 0; step < NST; step++) {
            if (step + 1 < NST) { loadA(step + 1, aN); loadB(step + 1, bN); }
            acc1 = __builtin_amdgcn_mfma_f32_32x32x16_bf16(aC, bC, acc1, 0, 0, 0);
            if (step + 1 < NST) { aC = aN; bC = bN; }
        }
    };

    stage_direct(0);
    __syncthreads();
    for (int kc = 0; kc < NCH; kc++) {
        const bool more = (kc + 1 < NCH);
        if (more) load_regs(kc + 1);
        compute(kc);
        if (more) {
            __syncthreads();
            write_regs();
            __syncthreads();
        }
    }

#pragma unroll
    for (int r = 0; r < 16; r++) {
        const int co = (r & 3) + 8 * (r >> 2) + 4 * kg;
        float vv = fmaxf(acc1[r] + b3[co], 0.f);
        unsigned short h, lo_;
        fsplit(vv, h, lo_);
        midL[((co >> 3) * 128 + pxl1) * 8 + (co & 7)] = h;
    }
    __syncthreads();

    f32x16 acc2[4];
#pragma unroll
    for (int pg = 0; pg < 4; pg++) acc2[pg] = (f32x16){};
#pragma unroll
    for (int pg = 0; pg < 4; pg++) {
#pragma unroll
        for (int ks = 0; ks < 2; ks++) {
            bf16x8 b = *(const bf16x8*)&midL[((ks * 2 + kg) * 128 + pg * 32 + ln) * 8];
            bf16x8 a = *(const bf16x8*)(w1H + ((size_t)(wv * 32 + ln)) * 32
                                        + ks * 16 + kg * 8);
            acc2[pg] = __builtin_amdgcn_mfma_f32_32x32x16_bf16(a, b, acc2[pg], 0, 0, 0);
        }
    }

    const int co32 = wv * 32;
#pragma unroll
    for (int pg = 0; pg < 4; pg++) {
        const int pxl = pg * 32 + ln;
        const int gy = r0 + pxl / W, gx = pxl % W;
#pragma unroll
        for (int rq = 0; rq < 4; rq++) {
            const int cb4 = co32 + 8 * rq + 4 * kg;
            float v[4];
#pragma unroll
            for (int i = 0; i < 4; i++) {
                const int r = rq * 4 + i;
                const int co = cb4 + i;
                size_t ra = ((size_t)n * 128 + co) * (H * W) + (size_t)gy * W + gx;
                float vv = acc2[pg][r] + b1[co] + Cf[ra];
                Cf[ra] = vv;
                v[i] = vv;
            }
            u64t uh = 0;
#pragma unroll
            for (int i = 0; i < 4; i++) {
                float pv = fmaxf(v[i], 0.f);
                unsigned short ph, pl;
                fsplit(pv, ph, pl);
                uh |= (u64t)ph << (16 * i);
            }
            size_t pa = (((size_t)n * CGO + (co32 >> 3) + rq) * H + gy) * (size_t)W * 8
                      + (size_t)gx * 8 + 4 * kg;
            *(u64t*)(outPH + pa) = uh;
        }
    }
}

// ============ bf16 MFMA transpose conv k=4 s=2 p=1 (r10 structure) ============
template<int CIP,int COUT,int HIN,int WIN,int CO2,int CC,int CO_PAD,
         bool PACK,bool WF32,bool ROUT>
__global__ __launch_bounds__(256) void convt_mfma(
    const unsigned short* __restrict__ inH,
    const unsigned short* __restrict__ wpH,
    const float* __restrict__ bias, float* __restrict__ outF,
    unsigned short* __restrict__ outPH)
{
    constexpr int HOUT = 2 * HIN, WOUT = 2 * WIN;
    constexpr int XHN  = WOUT / 128;
    constexpr int PS   = 3 * 68;
    constexpr int PLN  = CC * 2;
    constexpr int UN   = PS * PLN;
    constexpr int NCH  = CIP / (CC * 16);
    constexpr int CG   = CIP / 8;
    constexpr int CGO  = (COUT + 7) / 8;
    constexpr int REGU = (UN + 255) / 256;
    constexpr int NST  = CC * 4;

    __shared__ uint4 lbH[UN];

    const int tid = threadIdx.x;
    const int xh  = blockIdx.x % XHN;
    const int gr  = blockIdx.x / XHN;
    const int oy0 = (gr >> 1) * 4 + (gr & 1);
    const int co0 = blockIdx.y * (CO2 * 32);
    const int n   = blockIdx.z;

    const int ky0 = oy0 & 1;
    const int iyb = ((oy0 + ky0) >> 1) - 1;

    const int l  = tid & 63, wv = tid >> 6;
    const int pw = wv & 1, xb = wv >> 1;
    const int ln = l & 31, kg = l >> 5;

    const size_t inb = (size_t)n * CG * HIN * WIN;

    f32x16 acc[2][CO2];
#pragma unroll
    for (int r2 = 0; r2 < 2; r2++)
#pragma unroll
        for (int g = 0; g < CO2; g++) acc[r2][g] = (f32x16){};

    auto unit_load = [&](int u, int cgb, uint4& hv){
        int kgu = u / PS, pos = u - kgu * PS;
        int rr = pos / 68, cc = pos - rr * 68;
        int gy = iyb + rr, gx = xh * 64 + cc - 1;
        bool ok = ((unsigned)gy < (unsigned)HIN) && ((unsigned)gx < (unsigned)WIN);
        hv = make_uint4(0,0,0,0);
        if (ok) {
            size_t a = (inb + ((size_t)(cgb + kgu) * HIN + gy) * WIN + gx) * 8;
            hv = *(const uint4*)(inH + a);
        }
    };

    auto stage_direct = [&](int kc){
        for (int idx = tid; idx < UN; idx += 256) {
            uint4 hv;
            unit_load(idx, kc * PLN, hv);
            lbH[swzu(idx)] = hv;
        }
    };

    uint4 rvH[REGU];
    auto load_regs = [&](int kc){
#pragma unroll
        for (int rr = 0; rr < REGU; rr++) {
            int idx = tid + rr * 256;
            uint4 hv = make_uint4(0,0,0,0);
            if (idx < UN) unit_load(idx, kc * PLN, hv);
            rvH[rr] = hv;
        }
    };
    auto write_regs = [&](){
#pragma unroll
        for (int rr = 0; rr < REGU; rr++) {
            int idx = tid + rr * 256;
            if (idx < UN) lbH[swzu(idx)] = rvH[rr];
        }
    };

    auto compute = [&](int kc){
        bf16x8 aC[CO2], aN[CO2], bC[2], bN[2];
        auto loadA = [&](int step, bf16x8* a){
            const int ks = step / 4, tt = step - ks * 4;
            const int widx = (ky0 + 2 * (tt >> 1)) * 4 + (pw + 2 * (tt & 1));
#pragma unroll
            for (int g = 0; g < CO2; g++) {
                const int coA = co0 + g * 32 + ln;
                const size_t wo = ((size_t)widx * CO_PAD + coA) * CIP
                                + kc * (CC * 16) + ks * 16 + kg * 8;
                a[g] = *(const bf16x8*)(wpH + wo);
            }
        };
        auto loadB = [&](int step, bf16x8* bv){
            const int ks = step / 4, tt = step - ks * 4;
            const int ty = tt >> 1, tx = tt & 1;
#pragma unroll
            for (int r2 = 0; r2 < 2; r2++) {
                const int u = (ks * 2 + kg) * PS + (r2 + ty) * 68 + xb * 32 + ln + pw + tx;
                bv[r2] = *(const bf16x8*)&lbH[swzu(u)];
            }
        };
        loadA(0, aC); loadB(0, bC);
#pragma unroll
        for (int step = 0; step < NST; step++) {
            if (step + 1 < NST) { loadA(step + 1, aN); loadB(step + 1, bN); }
#pragma unroll
            for (int r2 = 0; r2 < 2; r2++)
#pragma unroll
                for (int g = 0; g < CO2; g++)
                    acc[r2][g] = __builtin_amdgcn_mfma_f32_32x32x16_bf16(
                        aC[g], bC[r2], acc[r2][g], 0, 0, 0);
            if (step + 1 < NST) {
#pragma unroll
                for (int g = 0; g < CO2; g++) aC[g] = aN[g];
#pragma unroll
                for (int r2 = 0; r2 < 2; r2++) bC[r2] = bN[r2];
            }
        }
    };

    stage_direct(0);
    __syncthreads();
    for (int kc = 0; kc < NCH; kc++) {
        const bool more = (kc + 1 < NCH);
        if (more) load_regs(kc + 1);
        compute(kc);
        if (more) {
            __syncthreads();
            write_regs();
            __syncthreads();
        }
    }

    const int ox = xh * 128 + pw + 2 * (xb * 32 + ln);
    const size_t HWo = (size_t)HOUT * WOUT;
#pragma unroll
    for (int r2 = 0; r2 < 2; r2++) {
        const int oy = oy0 + 2 * r2;
#pragma unroll
        for (int g = 0; g < CO2; g++) {
            const int co32 = co0 + g * 32;
#pragma unroll
            for (int rq = 0; rq < 4; rq++) {
                const int cb4 = co32 + 8 * rq + 4 * kg;
                float v[4];
#pragma unroll
                for (int i = 0; i < 4; i++) {
                    const int r = rq * 4 + i;
                    const int co = cb4 + i;
                    float bv = (co < COUT) ? bias[co] : 0.f;
                    float vv = acc[r2][g][r] + bv;
                    if (ROUT) vv = fmaxf(vv, 0.f);
                    if (WF32 && co < COUT)
                        outF[((size_t)n * COUT + co) * HWo + (size_t)oy * WOUT + ox] = vv;
                    v[i] = vv;
                }
                if (PACK) {
                    u64t uh = 0;
#pragma unroll
                    for (int i = 0; i < 4; i++) {
                        unsigned short ph, pl;
                        fsplit(v[i], ph, pl);
                        uh |= (u64t)ph << (16 * i);
                    }
                    size_t pa = (((size_t)n * CGO + (co32 >> 3) + rq) * HOUT + oy) * (size_t)WOUT * 8
                              + (size_t)ox * 8 + 4 * kg;
                    *(u64t*)(outPH + pa) = uh;
                }
            }
        }
    }
}

// ====== FUSED pre-VQ 1x1 + VQ + last-block finalize ======
__global__ __launch_bounds__(256) void vq_fused(
    const unsigned short* __restrict__ C1PH,
    const unsigned short* __restrict__ preH,
    const float* __restrict__ pre_b,
    const unsigned short* __restrict__ cbH, const unsigned short* __restrict__ cbL,
    const float* __restrict__ cnorm,
    unsigned short* __restrict__ IDX,
    float* __restrict__ ssep, int* __restrict__ hist,
    unsigned int* __restrict__ done,
    float* __restrict__ o_loss, float* __restrict__ o_perp)
{
    __shared__ unsigned short zH[128 * 72];
    __shared__ unsigned short zL[128 * 72];
    __shared__ float cnl[512];
    __shared__ int   hl[512];
    __shared__ int   lastBlk;

    const int tid = threadIdx.x;
    const int blk = blockIdx.x;

    for (int i = tid; i < 512; i += 256) { cnl[i] = cnorm[i]; hl[i] = 0; }

    const int l  = tid & 63, wv = tid >> 6;
    const int ln = l & 31, kg = l >> 5;
    const int tok = wv * 32 + ln;
    const int t   = blk * 128 + tok;
    const int n   = t >> 12, pix = t & 4095;

    // phase 1: z = pre_w x relu(C1) (1x1), kc ascending
    f32x16 az[2];
    az[0] = (f32x16){}; az[1] = (f32x16){};
#pragma unroll
    for (int kc = 0; kc < 8; kc++) {
        bf16x8 b = *(const bf16x8*)(C1PH + ((size_t)(n * 16 + kc * 2 + kg) * 4096 + pix) * 8);
#pragma unroll
        for (int g = 0; g < 2; g++) {
            bf16x8 a = *(const bf16x8*)(preH + ((size_t)(g * 32 + ln)) * 128
                                        + kc * 16 + kg * 8);
            az[g] = __builtin_amdgcn_mfma_f32_32x32x16_bf16(a, b, az[g], 0, 0, 0);
        }
    }
#pragma unroll
    for (int g = 0; g < 2; g++)
#pragma unroll
        for (int r = 0; r < 16; r++) {
            const int d = g * 32 + (r & 3) + 8 * (r >> 2) + 4 * kg;
            float vv = az[g][r] + pre_b[d];
            unsigned short h, lo_;
            fsplit(vv, h, lo_);
            zH[tok * 72 + d] = h;
            zL[tok * 72 + d] = lo_;
        }
    __syncthreads();

    // phase 2: VQ search
    float xn = 0.f;
#pragma unroll
    for (int j8 = 0; j8 < 8; j8++) {
        bf16x8 vH = *(const bf16x8*)&zH[tok * 72 + j8 * 8];
        bf16x8 vL = *(const bf16x8*)&zL[tok * 72 + j8 * 8];
#pragma unroll
        for (int j = 0; j < 8; j++) {
            float xv = bf2f((unsigned short)vH[j]) + bf2f((unsigned short)vL[j]);
            xn = fmaf(xv, xv, xn);
        }
    }

    float bm = 3.4e38f; int bidx = 0;
    for (int cg = 0; cg < 16; cg++) {
        f32x16 a0 = {}, a1 = {};
#pragma unroll
        for (int ks = 0; ks < 4; ks++) {
            const size_t wo = ((size_t)(cg * 32 + ln)) * 64 + ks * 16 + kg * 8;
            bf16x8 aH = *(const bf16x8*)(cbH + wo);
            bf16x8 aL = *(const bf16x8*)(cbL + wo);
            bf16x8 bH = *(const bf16x8*)&zH[tok * 72 + ks * 16 + kg * 8];
            bf16x8 bL = *(const bf16x8*)&zL[tok * 72 + ks * 16 + kg * 8];
            a0 = __builtin_amdgcn_mfma_f32_32x32x16_bf16(aH, bH, a0, 0, 0, 0);
            a1 = __builtin_amdgcn_mfma_f32_32x32x16_bf16(aH, bL, a1, 0, 0, 0);
            a1 = __builtin_amdgcn_mfma_f32_32x32x16_bf16(aL, bH, a1, 0, 0, 0);
        }
#pragma unroll
        for (int r = 0; r < 16; r++) {
            int m    = (r & 3) + 8 * (r >> 2) + 4 * kg;
            int code = cg * 32 + m;
            float s  = a0[r] + a1[r];
            float dm = cnl[code] - 2.f * s;
            if (dm < bm) { bm = dm; bidx = code; }
        }
    }

    float bm2 = __shfl_xor(bm, 32);
    int   bi2 = __shfl_xor(bidx, 32);
    if (bm2 < bm || (bm2 == bm && bi2 < bidx)) { bm = bm2; bidx = bi2; }

    if (kg == 0) IDX[t] = (unsigned short)bidx;

    float bestd = xn + bm;
    float c = (kg == 0) ? bestd : 0.f;
#pragma unroll
    for (int o = 32; o > 0; o >>= 1) c += __shfl_down(c, o, 64);
    if (l == 0) ssep[blk * 4 + wv] = c;
    if (kg == 0) atomicAdd(&hl[bidx], 1);
    __syncthreads();
    for (int i = tid; i < 512; i += 256) if (hl[i] > 0) atomicAdd(&hist[i], hl[i]);

    // last-block finalize (deterministic: reads fully-written SSE/HIST)
    if (tid == 0) {
        __threadfence();
        unsigned int prev = atomicAdd(done, 1u);
        lastBlk = (prev == gridDim.x - 1) ? 1 : 0;
    }
    __syncthreads();
    if (lastBlk) {
        __threadfence();
        float* red = (float*)zH;   // reuse LDS
        float h = 0.f;
        for (int i = tid; i < 512; i += 256) {
            float p = (float)hist[i] * (1.0f / 65536.0f);
            h -= p * logf(p + 1e-10f);
        }
        red[tid] = h;
        __syncthreads();
        for (int st = 128; st > 0; st >>= 1) {
            if (tid < st) red[tid] += red[tid + st];
            __syncthreads();
        }
        const float H = red[0];
        __syncthreads();
        float s = 0.f;
        for (int i = tid; i < 2048; i += 256) s += ssep[i];
        red[tid] = s;
        __syncthreads();
        for (int st = 128; st > 0; st >>= 1) {
            if (tid < st) red[tid] += red[tid + st];
            __syncthreads();
        }
        if (tid == 0) {
            *o_loss = 1.25f * red[0] / 4194304.0f;
            *o_perp = expf(H);
        }
    }
}

extern "C" void kernel_launch(void* const* d_in, const int* in_sizes, int n_in,
                              void* d_out, int out_size, void* d_ws, size_t ws_size,
                              hipStream_t stream)
{
    const float* x       = (const float*)d_in[0];
    const float* enc_w1  = (const float*)d_in[1];
    const float* enc_b1  = (const float*)d_in[2];
    const float* enc_w2  = (const float*)d_in[3];
    const float* enc_b2  = (const float*)d_in[4];
    const float* enc_w3  = (const float*)d_in[5];
    const float* enc_b3  = (const float*)d_in[6];
    const float* enc_rw3 = (const float*)d_in[7];
    const float* enc_rb3 = (const float*)d_in[8];
    const float* enc_rw1 = (const float*)d_in[9];
    const float* enc_rb1 = (const float*)d_in[10];
    const float* pre_w   = (const float*)d_in[11];
    const float* pre_b   = (const float*)d_in[12];
    const float* cb      = (const float*)d_in[13];
    const float* dec_w1  = (const float*)d_in[14];
    const float* dec_b1  = (const float*)d_in[15];
    const float* dec_rw3 = (const float*)d_in[16];
    const float* dec_rb3 = (const float*)d_in[17];
    const float* dec_rw1 = (const float*)d_in[18];
    const float* dec_rb1 = (const float*)d_in[19];
    const float* dw1     = (const float*)d_in[20];
    const float* db1     = (const float*)d_in[21];
    const float* dw2     = (const float*)d_in[22];
    const float* db2     = (const float*)d_in[23];

    float* o      = (float*)d_out;
    float* loss_p = o;
    float* recon  = o + 1;
    float* perp_p = o + 1 + 16 * 3 * 256 * 256;

    unsigned short* R1H = (unsigned short*)d_ws;
    unsigned short* R1L = R1H + 16777216;
    unsigned short* R2H = R1L + 16777216;
    unsigned short* R2L = R2H + 16777216;
    float* Cf  = (float*)(R2L + 16777216);
    float* SSE = Cf + 8388608;
    int*   HIST = (int*)(SSE + 2048);
    unsigned int* DONE = (unsigned int*)(HIST + 512);
    unsigned short* IDXb = (unsigned short*)(DONE + 8);   // 65536 tokens

    // packed activation aliases (lifetime-disjoint)
    unsigned short *xPH = R1H;
    unsigned short *BPH = R1H;
    unsigned short *dAPH = R1H;
    unsigned short *APH = R2H;
    unsigned short *C1PH = R2H;          // ping
    unsigned short *C2PH = R2L;          // pong

    unsigned short* wp_cur = (unsigned short*)(((size_t)(IDXb + 65536) + 31) & ~(size_t)31);
    auto carve = [&](size_t n_us) {
        unsigned short* p = wp_cur;
        wp_cur += ((n_us + 15) & ~(size_t)15);
        return p;
    };

    unsigned short *e1H = carve(16*64*16),  *e1L = carve(16*64*16);
    unsigned short *e2H = carve(16*128*64), *e2L = carve(16*128*64);
    unsigned short *e3H = carve(9*128*128), *e3L = carve(9*128*128);
    unsigned short *er3aH = carve(9*32*128), *er3aL = carve(9*32*128);
    unsigned short *er3bH = carve(9*32*128), *er3bL = carve(9*32*128);
    unsigned short *er1aH = carve(128*32),   *er1aL = carve(128*32);
    unsigned short *er1bH = carve(128*32),   *er1bL = carve(128*32);
    unsigned short *preH = carve(64*128),    *preL = carve(64*128);
    unsigned short *d1H  = carve(9*128*64),  *d1L  = carve(9*128*64);
    unsigned short *dr3aH = carve(9*32*128), *dr3aL = carve(9*32*128);
    unsigned short *dr3bH = carve(9*32*128), *dr3bL = carve(9*32*128);
    unsigned short *dr1aH = carve(128*32),   *dr1aL = carve(128*32);
    unsigned short *dr1bH = carve(128*32),   *dr1bL = carve(128*32);
    unsigned short *ct1H = carve(16*64*128), *ct1L = carve(16*64*128);
    unsigned short *ct2H = carve(16*32*64),  *ct2L = carve(16*32*64);
    unsigned short *cbH  = carve(512*64),    *cbL  = carve(512*64);
    float* CN = (float*)carve(1024);

    PrepArgs pa; int nb = 0;
    auto addPK = [&](int i, const float* w, unsigned short* hi, unsigned short* lo,
                     int Co, int Ci, int KK, int CoP, int CiP) {
        pa.d[i] = {w, hi, lo, Co, Ci, KK, CoP, CiP, nb};
        nb += (KK * CoP * CiP + 255) / 256;
    };
    addPK(0,  enc_w1, e1H, e1L, 64, 3, 16, 64, 16);
    addPK(1,  enc_w2, e2H, e2L, 128, 64, 16, 128, 64);
    addPK(2,  enc_w3, e3H, e3L, 128, 128, 9, 128, 128);
    addPK(3,  enc_rw3,            er3aH, er3aL, 32, 128, 9, 32, 128);
    addPK(4,  enc_rw3 + 32*128*9, er3bH, er3bL, 32, 128, 9, 32, 128);
    addPK(5,  enc_rw1,            er1aH, er1aL, 128, 32, 1, 128, 32);
    addPK(6,  enc_rw1 + 128*32,   er1bH, er1bL, 128, 32, 1, 128, 32);
    addPK(7,  pre_w, preH, preL, 64, 128, 1, 64, 128);
    addPK(8,  dec_w1, d1H, d1L, 128, 64, 9, 128, 64);
    addPK(9,  dec_rw3,            dr3aH, dr3aL, 32, 128, 9, 32, 128);
    addPK(10, dec_rw3 + 32*128*9, dr3bH, dr3bL, 32, 128, 9, 32, 128);
    addPK(11, dec_rw1,            dr1aH, dr1aL, 128, 32, 1, 128, 32);
    addPK(12, dec_rw1 + 128*32,   dr1bH, dr1bL, 128, 32, 1, 128, 32);
    addPK(13, dw1, ct1H, ct1L, 64, 128, 16, 64, 128);
    addPK(14, dw2, ct2H, ct2L, 3, 64, 16, 32, 64);
    addPK(15, cb,  cbH,  cbL,  512, 64, 1, 512, 64);
    pa.nd = 16;
    pa.nbw = nb;
    pa.x = x; pa.xPH = xPH; pa.cb = cb; pa.cn = CN; pa.hist = HIST; pa.done = DONE;
    prep<<<dim3(nb + 4096 + 2), dim3(256), 0, stream>>>(pa);

    const int N = 16;

    // ---- encoder ----
    conv_mfma<4,2,1, 16,64, 256,256, 128,128, 2,64, 2,2,2,1, 1, 64,
              true,false,false,false,true,false,false>
        <<<dim3(128,1,N),256,0,stream>>>(xPH, e1H, enc_b1, nullptr, nullptr, APH, nullptr,
                                         nullptr, nullptr);
    conv_mfma<4,2,1, 64,128, 128,128, 64,64, 2,64, 2,2,2,2, 1, 128,
              true,false,false,false,true,false,false>
        <<<dim3(32,1,N),256,0,stream>>>(APH, e2H, enc_b2, nullptr, nullptr, BPH, nullptr,
                                        nullptr, nullptr);
    conv_mfma<3,1,1, 128,128, 64,64, 64,64, 2,64, 2,2,2,2, 2, 128,
              true,true,false,true,false,false,false>
        <<<dim3(32,1,N),256,0,stream>>>(BPH, e3H, enc_b3, nullptr, Cf, C1PH, nullptr,
                                        nullptr, nullptr);
    fused_res<<<dim3(32,1,N),256,0,stream>>>(C1PH, er3aH, enc_rb3, er1aH, enc_rb1, Cf, C2PH);
    fused_res<<<dim3(32,1,N),256,0,stream>>>(C2PH, er3bH, enc_rb3 + 32, er1bH, enc_rb1 + 128, Cf, C1PH);

    // ---- fused pre-VQ 1x1 + VQ + finalize ----
    vq_fused<<<dim3(512), dim3(256), 0, stream>>>(C1PH, preH, pre_b, cbH, cbL, CN,
                                                  IDXb, SSE, HIST, DONE, loss_p, perp_p);

    // ---- decoder (dec1 gathers q rows by index) ----
    conv_mfma<3,1,1, 64,128, 64,64, 64,64, 2,64, 2,2,2,2, 2, 128,
              true,true,false,true,false,false,true>
        <<<dim3(32,1,N),256,0,stream>>>(nullptr, d1H, dec_b1, nullptr, Cf, C1PH, nullptr,
                                        cbH, IDXb);
    fused_res<<<dim3(32,1,N),256,0,stream>>>(C1PH, dr3aH, dec_rb3, dr1aH, dec_rb1, Cf, C2PH);
    fused_res<<<dim3(32,1,N),256,0,stream>>>(C2PH, dr3bH, dec_rb3 + 32, dr1bH, dec_rb1 + 128, Cf, C1PH);
    convt_mfma<128,64, 64,64, 2, 2, 64,  true,false,true>
        <<<dim3(64,1,N),256,0,stream>>>(C1PH, ct1H, db1, nullptr, dAPH);
    convt_mfma<64,3, 128,128, 1, 2, 32,  false,true,false>
        <<<dim3(256,1,N),256,0,stream>>>(dAPH, ct2H, db2, recon, nullptr);
}